// Round 1
// baseline (1211.060 us; speedup 1.0000x reference)
//
#include <hip/hip_runtime.h>
#include <hip/hip_bf16.h>

// EyeInput: out[i, :] = eye[x[i], :] where eye = identity(16384).
// Equivalent to one-hot scatter: zero the output, set out[i, x[i]] = 1.
// We never read the 1 GB eye input.

#define NB_FRAMES 16384

__global__ void onehot_scatter_kernel(const int* __restrict__ x,
                                      float* __restrict__ out,
                                      int n) {
    int i = blockIdx.x * blockDim.x + threadIdx.x;
    if (i < n) {
        int col = x[i];
        // guard against out-of-range just in case (reference would also index OOB)
        if (col >= 0 && col < NB_FRAMES) {
            out[(size_t)i * NB_FRAMES + col] = 1.0f;
        }
    }
}

extern "C" void kernel_launch(void* const* d_in, const int* in_sizes, int n_in,
                              void* d_out, int out_size, void* d_ws, size_t ws_size,
                              hipStream_t stream) {
    // d_in[0] = eye (float32, 16384*16384) -- unused
    // d_in[1] = x   (int32, 4096)
    const int* x = (const int*)d_in[1];
    float* out = (float*)d_out;
    int n = in_sizes[1];  // 4096 rows

    // Zero the entire output (harness poisons it with 0xAA before every launch).
    hipMemsetAsync(out, 0, (size_t)out_size * sizeof(float), stream);

    // Scatter the ones: one thread per row.
    int block = 256;
    int grid = (n + block - 1) / block;
    onehot_scatter_kernel<<<grid, block, 0, stream>>>(x, out, n);
}